// Round 1
// baseline (438.407 us; speedup 1.0000x reference)
//
#include <hip/hip_runtime.h>

#define TLEN  4096
#define NROWS 4096
#define UN    8          // float4 loads per iteration -> 16 timesteps/iter

#if __has_builtin(__builtin_amdgcn_exp2f)
__device__ __forceinline__ float fexp2(float x) { return __builtin_amdgcn_exp2f(x); }
#else
__device__ __forceinline__ float fexp2(float x) { return exp2f(x); }
#endif

#if __has_builtin(__builtin_amdgcn_rcpf)
__device__ __forceinline__ float frcp(float x) { return __builtin_amdgcn_rcpf(x); }
#else
__device__ __forceinline__ float frcp(float x) { return 1.0f / x; }
#endif

// Swap adjacent lanes (lane ^ 1) via DPP quad_perm [1,0,3,2] = 0xB1.
// VALU-latency cross-lane; much cheaper on the serial chain than
// __shfl_xor (which lowers to ds_bpermute, ~25+ cyc lgkm latency).
__device__ __forceinline__ float lane_swap1(float v) {
    int r = __builtin_amdgcn_update_dpp(0, __float_as_int(v), 0xB1, 0xF, 0xF, true);
    return __int_as_float(r);
}

struct LaneConst {
    float c1_in, c0_in;   // input sigmoid:  sig = rcp(1 + exp2(c1*pre + c0))
    float c1_sf, c0_sf;   // self-state sigmoid
    float c1_ot, c0_ot;   // outgoing-cross sigmoid (general path only)
    float gS_in, gS_cr, gS_sf;   // g/cap            coefficients (S accumulation)
    float gP_in, gP_cr, gP_sf;   // g*pot/cap        coefficients (P accumulation)
};

// One timestep of one chain (x on even lanes, y on odd lanes).
// s_{t+1} = s + (P - S*s), S = sum g' * sig, P = sum g'*pot * sig.
template<bool SHARED>
__device__ __forceinline__ float do_step(float s, float pre_in, const LaneConst& k) {
    float e_in = fexp2(__builtin_fmaf(k.c1_in, pre_in, k.c0_in));
    float e_sf = fexp2(__builtin_fmaf(k.c1_sf, s, k.c0_sf));
    float sig_in = frcp(1.0f + e_in);
    float sig_sf = frcp(1.0f + e_sf);
    float sig_ot;
    if (SHARED) {
        sig_ot = sig_sf;  // (mean,std) of self dir == cross dir: reuse sigmoid
    } else {
        float e_ot = fexp2(__builtin_fmaf(k.c1_ot, s, k.c0_ot));
        sig_ot = frcp(1.0f + e_ot);
    }
    // receive partner's outgoing sigmoid (sig of the OTHER state with the
    // incoming-cross direction's (mean,std)); apply our own g',pot coeffs.
    float sig_cr = lane_swap1(sig_ot);
    float S = __builtin_fmaf(k.gS_in, sig_in, __builtin_fmaf(k.gS_cr, sig_cr, k.gS_sf * sig_sf));
    float P = __builtin_fmaf(k.gP_in, sig_in, __builtin_fmaf(k.gP_cr, sig_cr, k.gP_sf * sig_sf));
    return s + __builtin_fmaf(S, -s, P);
}

template<bool SHARED>
__device__ __forceinline__ void run_scan(const float* __restrict__ inp,
                                         const float* __restrict__ prm,
                                         float* __restrict__ out) {
    const int tid = blockIdx.x * 64 + threadIdx.x;
    const int row = tid >> 1;
    const int par = tid & 1;   // 0: x-chain, 1: y-chain

    const float L2E = 1.4426950408889634f;
    // param group bases: ax=2, by=6, xy=10, yx=14, xx=18, yy=22
    const int inB = par ? 6  : 2;    // input direction   (by / ax)
    const int sfB = par ? 22 : 18;   // self direction    (yy / xx)
    const int otB = par ? 14 : 10;   // outgoing cross    (yx / xy)  [we compute sig, partner consumes]
    const int crB = par ? 10 : 14;   // incoming cross    (xy / yx)  [coefficients we apply]

    const float invc = 1.0f / prm[par];   // 1/cap of OUR state (full-precision div, once)

    LaneConst k;
    {
        float sd = prm[inB + 2], mn = prm[inB + 1];
        k.c1_in = -sd * L2E; k.c0_in = sd * mn * L2E;
        sd = prm[sfB + 2]; mn = prm[sfB + 1];
        k.c1_sf = -sd * L2E; k.c0_sf = sd * mn * L2E;
        sd = prm[otB + 2]; mn = prm[otB + 1];
        k.c1_ot = -sd * L2E; k.c0_ot = sd * mn * L2E;
        k.gS_in = prm[inB] * invc; k.gP_in = k.gS_in * prm[inB + 3];
        k.gS_sf = prm[sfB] * invc; k.gP_sf = k.gS_sf * prm[sfB + 3];
        k.gS_cr = prm[crB] * invc; k.gP_cr = k.gS_cr * prm[crB + 3];
    }

    // Both lanes of a pair load the same float4 (a_t,b_t,a_{t+1},b_{t+1});
    // duplicate addresses coalesce into one request.
    const float4* __restrict__ src = (const float4*)inp + (size_t)row * (TLEN / 2);
    float* __restrict__ dst = out + (size_t)row * (TLEN * 2) + par;

    float s = par ? 1.0f : 0.0f;   // x0 = 0, y0 = 1

    float4 cur[UN], nxt[UN];
#pragma unroll
    for (int j = 0; j < UN; ++j) cur[j] = src[j];

    const int NIT = TLEN / (2 * UN);
    for (int it = 0; it < NIT; ++it) {
        // software pipeline: issue next iteration's loads before computing;
        // the wait lands at the rotation below, ~16 steps (~800 cyc) later.
        if (it + 1 < NIT) {
#pragma unroll
            for (int j = 0; j < UN; ++j) nxt[j] = src[(it + 1) * UN + j];
        }
        float* dptr = dst + it * (UN * 4);
#pragma unroll
        for (int j = 0; j < UN; ++j) {
            float4 f = cur[j];
            s = do_step<SHARED>(s, par ? f.y : f.x, k);
            dptr[j * 4] = s;            // out[row, t, par]
            s = do_step<SHARED>(s, par ? f.w : f.z, k);
            dptr[j * 4 + 2] = s;        // out[row, t+1, par]
        }
#pragma unroll
        for (int j = 0; j < UN; ++j) cur[j] = nxt[j];
    }
}

__global__ __launch_bounds__(64, 1)
void memcell_scan(const float* __restrict__ inp,
                  const float* __restrict__ prm,
                  float* __restrict__ out) {
    // Wave-uniform runtime check: if the state-sigmoid (mean,std) are shared
    // between self and cross directions (xx==xy and yy==yx), one sigmoid per
    // lane serves both its own update and the partner's.
    const bool shared = (prm[11] == prm[19]) && (prm[12] == prm[20]) &&
                        (prm[15] == prm[23]) && (prm[16] == prm[24]);
    if (shared) run_scan<true>(inp, prm, out);
    else        run_scan<false>(inp, prm, out);
}

extern "C" void kernel_launch(void* const* d_in, const int* in_sizes, int n_in,
                              void* d_out, int out_size, void* d_ws, size_t ws_size,
                              hipStream_t stream) {
    (void)in_sizes; (void)n_in; (void)d_ws; (void)ws_size; (void)out_size;
    const float* inp = (const float*)d_in[0];
    const float* prm = (const float*)d_in[1];
    float* out = (float*)d_out;
    // 2 lanes per row: 8192 threads, 64-thread (1-wave) blocks spread across CUs.
    memcell_scan<<<dim3((NROWS * 2) / 64), dim3(64), 0, stream>>>(inp, prm, out);
}